// Round 1
// baseline (325.724 us; speedup 1.0000x reference)
//
#include <hip/hip_runtime.h>
#include <math.h>

#define HH 64
#define WW 64
#define KS 5
#define CPP 8
#define NPOS 48
#define CHAN (NPOS * CPP)   // 384
#define NBATCH 32

// DPP wave shifts: full-rate VALU cross-lane, no LDS pipe, no lgkmcnt.
// wave_shr:1 (0x138): lane i <- lane i-1.  wave_shl:1 (0x130): lane i <- lane i+1.
__device__ __forceinline__ float dpp_shr1(float v) {
    return __int_as_float(__builtin_amdgcn_mov_dpp(__float_as_int(v), 0x138, 0xF, 0xF, true));
}
__device__ __forceinline__ float dpp_shl1(float v) {
    return __int_as_float(__builtin_amdgcn_mov_dpp(__float_as_int(v), 0x130, 0xF, 0xF, true));
}

// One wave per 64x64 plane, as before, but ALL global traffic is dwordx4:
//  - loads: 4 source-aligned rows per wave-instruction (lane l -> row l>>4,
//    cols 4*(l&15)..+3), bounced through a 1KB wave-private LDS buffer; the
//    per-lane shifted re-read (ds_read_b32 at col sxc) performs the dx shift
//    and the 4rows-per-wave -> lane=column corner-turn in one step.
//  - stores: completed output rows buffered in LDS (ds_write_b32, lane=col),
//    then written 4 rows at a time with global_store_dwordx4.
// Horizontal 5-tap via DPP shifts + masked weights, vertical 5-tap via
// 5-register sliding window — arithmetic identical to the dword version.
__global__ __launch_bounds__(256, 4)
void displace_dpp_kernel(const float* __restrict__ x,
                         const float* __restrict__ off,
                         float* __restrict__ out)
{
    const int t    = threadIdx.x;
    const int lane = t & 63;
    const int wid  = t >> 6;
    const int plane = __builtin_amdgcn_readfirstlane(blockIdx.x * 4 + wid);
    const int p = (plane % CHAN) / CPP;          // position index (wave-uniform)

    // wave-private LDS: no __syncthreads needed anywhere (lgkmcnt orders it)
    __shared__ __align__(16) float lin [4][4][WW];   // [wave][row-in-chunk][col]
    __shared__ __align__(16) float lout[4][4][WW];   // [wave][row-in-chunk][col]
    float (* __restrict__ inbuf)[WW]  = lin[wid];
    float (* __restrict__ outbuf)[WW] = lout[wid];

    const float* __restrict__ src = x   + (size_t)plane * (HH * WW);
    float*       __restrict__ dst = out + (size_t)plane * (HH * WW);

    // --- offset -> integer shift + separable Gaussian weights (sigma=0.5) ---
    const float offx = off[2 * p + 0];
    const float offy = off[2 * p + 1];
    const float rxf = rintf(offx), ryf = rintf(offy);
    const int   dx = (int)rxf,     dy = (int)ryf;
    const float subx = offx - rxf, suby = offy - ryf;

    float wxr[KS], wy[KS];
    float sumx = 0.f, sumy = 0.f;
    #pragma unroll
    for (int k = 0; k < KS; ++k) {
        const float ax = (float)(k - 2) + subx;
        const float ay = (float)(k - 2) + suby;
        wxr[k] = __expf(-2.0f * ax * ax);
        wy[k]  = __expf(-2.0f * ay * ay);
        sumx += wxr[k];
        sumy += wy[k];
    }
    const float inv = 1.0f / (sumx * sumy);

    // tap k reads displaced column lane+k-2: zero if outside [0,W) (conv pad).
    float wxm[KS];
    #pragma unroll
    for (int k = 0; k < KS; ++k) {
        const int sl = lane + (k - 2);
        wxm[k] = ((unsigned)sl < (unsigned)WW) ? wxr[k] * inv : 0.0f;
    }

    // per-lane source column for displaced value D[lane] = row[lane-dx]
    const int   sx  = lane - dx;
    const float mx  = ((unsigned)sx < (unsigned)WW) ? 1.0f : 0.0f;
    const int   sxc = min(max(sx, 0), WW - 1);

    const int g  = lane >> 4;     // row-in-chunk this lane loads/stores
    const int pq = lane & 15;     // float4 slot within the row

    float hb[5];                  // sliding window of horizontally-filtered rows

    // prologue: load chunk 0 (displaced rows -2..1)
    float4 cur;
    {
        const int yy  = -2 + g;
        const int sy  = yy - dy;
        const int syc = min(max(sy, 0), HH - 1);
        cur = *reinterpret_cast<const float4*>(src + syc * WW + pq * 4);
    }

    #pragma unroll
    for (int j = 0; j < 17; ++j) {
        // stage chunk j (displaced rows 4j-2 .. 4j+1), source-aligned
        *reinterpret_cast<float4*>(&inbuf[g][pq * 4]) = cur;

        // prefetch chunk j+1
        if (j < 16) {
            const int yy  = 4 * (j + 1) - 2 + g;
            const int sy  = yy - dy;
            const int syc = min(max(sy, 0), HH - 1);
            cur = *reinterpret_cast<const float4*>(src + syc * WW + pq * 4);
        }

        #pragma unroll
        for (int r = 0; r < 4; ++r) {
            const int  i  = 4 * j + r;        // global iteration index
            const int  yy = i - 2;            // displaced row
            const int  sy = yy - dy;          // source row
            const bool rowok = (((unsigned)yy < (unsigned)HH) &
                                ((unsigned)sy < (unsigned)HH));

            const float v   = inbuf[r][sxc] * mx;   // D[lane] (masked)
            const float sm1 = dpp_shr1(v);          // D[lane-1]
            const float sm2 = dpp_shr1(sm1);        // D[lane-2]
            const float sp1 = dpp_shl1(v);          // D[lane+1]
            const float sp2 = dpp_shl1(sp1);        // D[lane+2]

            float h = wxm[0] * sm2;
            h = fmaf(wxm[1], sm1, h);
            h = fmaf(wxm[2], v,   h);
            h = fmaf(wxm[3], sp1, h);
            h = fmaf(wxm[4], sp2, h);
            hb[i % 5] = rowok ? h : 0.0f;

            if (i >= 4) {
                // output row y = i-4 = 4(j-1)+r  -> slot r
                float a = wy[0] * hb[(i - 4) % 5];
                a = fmaf(wy[1], hb[(i - 3) % 5], a);
                a = fmaf(wy[2], hb[(i - 2) % 5], a);
                a = fmaf(wy[3], hb[(i - 1) % 5], a);
                a = fmaf(wy[4], hb[(i - 0) % 5], a);
                outbuf[r][lane] = a;
            }
        }

        // flush completed output chunk (rows 4(j-1) .. 4(j-1)+3) as dwordx4
        if (j >= 1) {
            const int ybase = 4 * (j - 1);
            const float4 o = *reinterpret_cast<const float4*>(&outbuf[g][pq * 4]);
            *reinterpret_cast<float4*>(dst + (ybase + g) * WW + pq * 4) = o;
        }
    }
}

extern "C" void kernel_launch(void* const* d_in, const int* in_sizes, int n_in,
                              void* d_out, int out_size, void* d_ws, size_t ws_size,
                              hipStream_t stream) {
    const float* x   = (const float*)d_in[0];
    const float* off = (const float*)d_in[1];
    float* out = (float*)d_out;

    // one wave per plane; 4 waves (planes) per 256-thread block
    const int blocks = NBATCH * CHAN / 4;   // 3072
    displace_dpp_kernel<<<blocks, 256, 0, stream>>>(x, off, out);
}

// Round 3
// 316.272 us; speedup vs baseline: 1.0299x; 1.0299x over previous
//
#include <hip/hip_runtime.h>
#include <math.h>

#define HH 64
#define WW 64
#define KS 5
#define CPP 8
#define NPOS 48
#define CHAN (NPOS * CPP)   // 384
#define NBATCH 32

// DPP wave shifts: full-rate VALU cross-lane, no LDS pipe, no lgkmcnt.
// wave_shr:1 (0x138): lane i <- lane i-1.  wave_shl:1 (0x130): lane i <- lane i+1.
__device__ __forceinline__ float dpp_shr1(float v) {
    return __int_as_float(__builtin_amdgcn_mov_dpp(__float_as_int(v), 0x138, 0xF, 0xF, true));
}
__device__ __forceinline__ float dpp_shl1(float v) {
    return __int_as_float(__builtin_amdgcn_mov_dpp(__float_as_int(v), 0x130, 0xF, 0xF, true));
}

// One wave per 64x64 plane. Lane = x column. Per displaced row: one coalesced
// global_load_dword (shift dx is wave-uniform, folded into per-lane source col),
// horizontal 5-tap via 4 chained DPP wave shifts + masked weights (conv zero-pad
// + source-validity + normalization folded into wxm / mx), vertical 5-tap via
// 5-register sliding window. Plane index readfirstlane'd -> scalar base addressing.
// R1 experiment (dwordx4 via LDS corner-turn) was neutral-to-negative: instruction
// width is not the limiter at 256B/inst contiguous rows. Reverted; stores are now
// nontemporal (output is write-once, never re-read -> keep it out of L2).
// R2 was an infra failure (container acquisition), not a kernel failure — resubmit.
__global__ __launch_bounds__(256)
void displace_dpp_kernel(const float* __restrict__ x,
                         const float* __restrict__ off,
                         float* __restrict__ out)
{
    const int t    = threadIdx.x;
    const int lane = t & 63;
    const int plane = __builtin_amdgcn_readfirstlane(blockIdx.x * 4 + (t >> 6));
    const int p = (plane % CHAN) / CPP;          // position index (wave-uniform)

    const float* __restrict__ src = x   + (size_t)plane * (HH * WW);
    float*       __restrict__ dst = out + (size_t)plane * (HH * WW);

    // --- offset -> integer shift + separable Gaussian weights (sigma=0.5) ---
    const float offx = off[2 * p + 0];
    const float offy = off[2 * p + 1];
    const float rxf = rintf(offx), ryf = rintf(offy);
    const int   dx = (int)rxf,     dy = (int)ryf;
    const float subx = offx - rxf, suby = offy - ryf;

    float wxr[KS], wy[KS];
    float sumx = 0.f, sumy = 0.f;
    #pragma unroll
    for (int k = 0; k < KS; ++k) {
        const float ax = (float)(k - 2) + subx;
        const float ay = (float)(k - 2) + suby;
        wxr[k] = __expf(-2.0f * ax * ax);
        wy[k]  = __expf(-2.0f * ay * ay);
        sumx += wxr[k];
        sumy += wy[k];
    }
    const float inv = 1.0f / (sumx * sumy);

    // tap k reads displaced column lane+k-2: zero if outside [0,W) (conv pad).
    // Fold full 2D normalization in. (Neighbor's own source-validity is folded
    // into that neighbor's loaded value via mx.)
    float wxm[KS];
    #pragma unroll
    for (int k = 0; k < KS; ++k) {
        const int sl = lane + (k - 2);
        wxm[k] = ((unsigned)sl < (unsigned)WW) ? wxr[k] * inv : 0.0f;
    }

    // per-lane source column for displaced value D[lane] = src[.][lane-dx]
    const int   sx  = lane - dx;
    const float mx  = ((unsigned)sx < (unsigned)WW) ? 1.0f : 0.0f;
    const int   sxc = min(max(sx, 0), WW - 1);

    float hb[5];   // sliding window of horizontally-filtered rows

    #pragma unroll
    for (int i = 0; i < HH + 4; ++i) {
        const int  yy = i - 2;            // displaced row
        const int  sy = yy - dy;          // source row
        const bool rowok = (((unsigned)yy < (unsigned)HH) & ((unsigned)sy < (unsigned)HH));
        const int  syc = min(max(sy, 0), HH - 1);

        const float v   = src[syc * WW + sxc] * mx;   // D[lane] (masked)
        const float sm1 = dpp_shr1(v);                // D[lane-1]
        const float sm2 = dpp_shr1(sm1);              // D[lane-2]
        const float sp1 = dpp_shl1(v);                // D[lane+1]
        const float sp2 = dpp_shl1(sp1);              // D[lane+2]

        float h = wxm[0] * sm2;
        h = fmaf(wxm[1], sm1, h);
        h = fmaf(wxm[2], v,   h);
        h = fmaf(wxm[3], sp1, h);
        h = fmaf(wxm[4], sp2, h);
        hb[i % 5] = rowok ? h : 0.0f;

        if (i >= 4) {
            const int y = i - 4;
            float a = wy[0] * hb[(i - 4) % 5];
            a = fmaf(wy[1], hb[(i - 3) % 5], a);
            a = fmaf(wy[2], hb[(i - 2) % 5], a);
            a = fmaf(wy[3], hb[(i - 1) % 5], a);
            a = fmaf(wy[4], hb[(i - 0) % 5], a);
            __builtin_nontemporal_store(a, dst + y * WW + lane);
        }
    }
}

extern "C" void kernel_launch(void* const* d_in, const int* in_sizes, int n_in,
                              void* d_out, int out_size, void* d_ws, size_t ws_size,
                              hipStream_t stream) {
    const float* x   = (const float*)d_in[0];
    const float* off = (const float*)d_in[1];
    float* out = (float*)d_out;

    // one wave per plane; 4 waves (planes) per 256-thread block
    const int blocks = NBATCH * CHAN / 4;   // 3072
    displace_dpp_kernel<<<blocks, 256, 0, stream>>>(x, off, out);
}